// Round 3
// baseline (298.603 us; speedup 1.0000x reference)
//
#include <hip/hip_runtime.h>
#include <hip/hip_cooperative_groups.h>
#include <math.h>

namespace cg = cooperative_groups;

// FSQuantizer v3: single cooperative kernel (h,g register-resident across grid syncs).
// z (32,512,4096) f32 -> zhat f32 + commit_loss + perplexity.
// 512 blocks x 128 threads (2 waves/block, 2 blocks/CU co-resident).
// Each thread owns 2 rows (t, t+1) of n=(b,t); float2 loads/stores along t.

namespace {
constexpr int Cv = 512, Tv = 4096, Bv = 32;
constexpr int Nv = Bv * Tv;                       // 131072 rows
constexpr long long TOTv = (long long)Nv * Cv;    // 67108864
constexpr int NBLK = 512;
constexpr int NWAVE = NBLK * 2;                   // 1024 waves

// ws layout (bytes)
constexpr size_t OFF_BS = 0;                                  // [NWAVE][10] f64 stats
constexpr size_t OFF_GR = OFF_BS + (size_t)NWAVE * 10 * 8;    // [16] f64 gram
constexpr size_t OFF_CP = OFF_GR + 16 * 8;                    // [NWAVE] f64 commit partials
constexpr size_t OFF_CT = OFF_CP + (size_t)NWAVE * 8;         // [1000] u32 counts
}

__global__ __launch_bounds__(128) void fsq_main(
    const float* __restrict__ z, const float* __restrict__ W_in,
    const float* __restrict__ b_in, const float* __restrict__ gamma,
    const float* __restrict__ beta, const float* __restrict__ W_out,
    const float* __restrict__ b_out, float* __restrict__ out,
    double* __restrict__ bs, double* __restrict__ gram,
    double* __restrict__ cp, unsigned* __restrict__ counts, int out_size)
{
    cg::grid_group grid = cg::this_grid();
    __shared__ float s_wi[512][4];   // W_in [c][e]
    __shared__ float s_wo[512][4];   // W_out^T [c][e]
    __shared__ float s_bo[512];

    const int tid = threadIdx.x;
    const int lane = tid & 63;
    const int bid = blockIdx.x;
    const int wid = bid * 2 + (tid >> 6);
    const int b = bid >> 4;                  // 16 t-tiles per b
    const int t0 = (bid & 15) << 8;          // 256 t per block

    if (bid == 0) {
        for (int i = tid; i < 1000; i += 128) counts[i] = 0;
    }
    for (int i = tid; i < 512; i += 128) {
        *(float4*)&s_wi[i][0] = *(const float4*)(W_in + i * 4);
        s_wo[i][0] = W_out[i];
        s_wo[i][1] = W_out[512 + i];
        s_wo[i][2] = W_out[1024 + i];
        s_wo[i][3] = W_out[1536 + i];
        s_bo[i] = b_out[i];
    }
    __syncthreads();

    // ---- phase 1: stream z, accumulate h/g/z2/zb in registers ----
    float h[2][4] = {}, g[2][4] = {};
    float z2 = 0.f, zbp = 0.f;
    const float* zp = z + (size_t)b * Cv * Tv + t0 + tid * 2;
#pragma unroll 8
    for (int c = 0; c < 512; ++c) {
        const float2 zv = *(const float2*)(zp + (size_t)c * Tv);
        const float4 wi = *(const float4*)&s_wi[c][0];
        const float4 wo = *(const float4*)&s_wo[c][0];
        const float bo = s_bo[c];
        const float zr[2] = {zv.x, zv.y};
#pragma unroll
        for (int j = 0; j < 2; ++j) {
            h[j][0] = fmaf(zr[j], wi.x, h[j][0]);
            h[j][1] = fmaf(zr[j], wi.y, h[j][1]);
            h[j][2] = fmaf(zr[j], wi.z, h[j][2]);
            h[j][3] = fmaf(zr[j], wi.w, h[j][3]);
            g[j][0] = fmaf(zr[j], wo.x, g[j][0]);
            g[j][1] = fmaf(zr[j], wo.y, g[j][1]);
            g[j][2] = fmaf(zr[j], wo.z, g[j][2]);
            g[j][3] = fmaf(zr[j], wo.w, g[j][3]);
            z2 = fmaf(zr[j], zr[j], z2);
        }
        zbp = fmaf(zv.x + zv.y, bo, zbp);
    }
    {
        const float bi0 = b_in[0], bi1 = b_in[1], bi2 = b_in[2], bi3 = b_in[3];
#pragma unroll
        for (int j = 0; j < 2; ++j) {
            h[j][0] += bi0; h[j][1] += bi1; h[j][2] += bi2; h[j][3] += bi3;
        }
    }

    // per-wave stats: Sh[4], Sh2[4], z2, zb
    {
        double st[10];
#pragma unroll
        for (int e = 0; e < 4; ++e) {
            const double h0 = (double)h[0][e], h1 = (double)h[1][e];
            st[e] = h0 + h1;
            st[4 + e] = h0 * h0 + h1 * h1;
        }
        st[8] = (double)z2; st[9] = (double)zbp;
#pragma unroll
        for (int k = 0; k < 10; ++k) {
#pragma unroll
            for (int m = 1; m < 64; m <<= 1) st[k] += __shfl_xor(st[k], m, 64);
        }
        if (lane == 0) {
#pragma unroll
            for (int k = 0; k < 10; ++k) bs[(size_t)wid * 10 + k] = st[k];
        }
    }

    // block 511 wave 0: Gram of W_out rows + v + s0 (data-independent)
    if (bid == NBLK - 1 && tid < 64) {
        double a[15] = {};
        for (int k = 0; k < 8; ++k) {
            const int c = lane + k * 64;
            const double w0 = (double)W_out[c], w1 = (double)W_out[512 + c];
            const double w2 = (double)W_out[1024 + c], w3 = (double)W_out[1536 + c];
            const double bb = (double)b_out[c];
            a[0] += w0 * w0; a[1] += w0 * w1; a[2] += w0 * w2; a[3] += w0 * w3;
            a[4] += w1 * w1; a[5] += w1 * w2; a[6] += w1 * w3;
            a[7] += w2 * w2; a[8] += w2 * w3; a[9] += w3 * w3;
            a[10] += w0 * bb; a[11] += w1 * bb; a[12] += w2 * bb; a[13] += w3 * bb;
            a[14] += bb * bb;
        }
#pragma unroll
        for (int k = 0; k < 15; ++k) {
#pragma unroll
            for (int m = 1; m < 64; m <<= 1) a[k] += __shfl_xor(a[k], m, 64);
        }
        if (lane == 0) {
#pragma unroll
            for (int k = 0; k < 15; ++k) gram[k] = a[k];
        }
    }

    grid.sync();

    // ---- phase 2: redundant per-wave BN consts ----
    double a8[8] = {};
    for (int k = 0; k < 16; ++k) {
        const double* r = bs + (size_t)(lane + k * 64) * 10;
#pragma unroll
        for (int q = 0; q < 8; ++q) a8[q] += r[q];
    }
#pragma unroll
    for (int q = 0; q < 8; ++q) {
#pragma unroll
        for (int m = 1; m < 64; m <<= 1) a8[q] += __shfl_xor(a8[q], m, 64);
    }
    double sc[4], bi[4];
    {
        const double Ninv = 1.0 / (double)Nv;
#pragma unroll
        for (int e = 0; e < 4; ++e) {
            const double mu = a8[e] * Ninv;
            const double var = a8[4 + e] * Ninv - mu * mu;   // biased, matches jnp.var
            sc[e] = (double)gamma[e] / sqrt(var + 1e-5);
            bi[e] = (double)beta[e] - mu * sc[e];
        }
    }
    double gr[15];
#pragma unroll
    for (int k = 0; k < 15; ++k) gr[k] = gram[k];

    constexpr double hl0 = (8.0 - 1.0) * (1.0 - 1e-3) / 2.0;   // 3.4965
    constexpr double hl1 = (5.0 - 1.0) * (1.0 - 1e-3) / 2.0;   // 1.998
    const double shift0 = tan(0.5 / hl0);

    // quantize 2 rows, histogram, commit partial
    float zn[2][4];
    double qsum = 0.0;
#pragma unroll
    for (int j = 0; j < 2; ++j) {
        const double hn0 = fma((double)h[j][0], sc[0], bi[0]);
        const double hn1 = fma((double)h[j][1], sc[1], bi[1]);
        const double hn2 = fma((double)h[j][2], sc[2], bi[2]);
        const double hn3 = fma((double)h[j][3], sc[3], bi[3]);
        const double r0 = rint(tanh(hn0 + shift0) * hl0 - 0.5);  // [-4,3]
        const double r1 = rint(tanh(hn1) * hl1);                 // [-2,2]
        const double r2 = rint(tanh(hn2) * hl1);
        const double r3 = rint(tanh(hn3) * hl1);
        const double zd0 = r0 * 0.25, zd1 = r1 * 0.5, zd2 = r2 * 0.5, zd3 = r3 * 0.5;
        zn[j][0] = (float)zd0; zn[j][1] = (float)zd1;
        zn[j][2] = (float)zd2; zn[j][3] = (float)zd3;
        const int code = ((int)r0 + 4) + ((int)r1 + 2) * 8 + ((int)r2 + 2) * 40
                       + ((int)r3 + 2) * 200;
        atomicAdd(&counts[code], 1u);
        const double cg = zd0 * (double)g[j][0] + zd1 * (double)g[j][1]
                        + zd2 * (double)g[j][2] + zd3 * (double)g[j][3];
        double q = gr[14]
                 + 2.0 * (zd0 * gr[10] + zd1 * gr[11] + zd2 * gr[12] + zd3 * gr[13])
                 + zd0 * zd0 * gr[0] + zd1 * zd1 * gr[4]
                 + zd2 * zd2 * gr[7] + zd3 * zd3 * gr[9]
                 + 2.0 * (zd0 * zd1 * gr[1] + zd0 * zd2 * gr[2] + zd0 * zd3 * gr[3]
                        + zd1 * zd2 * gr[5] + zd1 * zd3 * gr[6] + zd2 * zd3 * gr[8]);
        qsum += q - 2.0 * cg;
    }
#pragma unroll
    for (int m = 1; m < 64; m <<= 1) qsum += __shfl_xor(qsum, m, 64);
    if (lane == 0) cp[wid] = qsum;

    // write zhat: float2 stores, coalesced along t
    float* op = out + (size_t)b * Cv * Tv + t0 + tid * 2;
#pragma unroll 4
    for (int c = 0; c < 512; ++c) {
        const float4 wo = *(const float4*)&s_wo[c][0];
        const float bo = s_bo[c];
        float2 o;
        o.x = fmaf(zn[0][0], wo.x, fmaf(zn[0][1], wo.y,
              fmaf(zn[0][2], wo.z, fmaf(zn[0][3], wo.w, bo))));
        o.y = fmaf(zn[1][0], wo.x, fmaf(zn[1][1], wo.y,
              fmaf(zn[1][2], wo.z, fmaf(zn[1][3], wo.w, bo))));
        *(float2*)(op + (size_t)c * Tv) = o;
    }

    grid.sync();

    // ---- phase 3: block 0 finalizes scalars ----
    if (bid == 0 && tid < 64) {
        double csv = 0.0, z2t = 0.0, zbt = 0.0, pl = 0.0;
        for (int k = 0; k < 16; ++k) {
            csv += cp[lane + k * 64];
            const double* r = bs + (size_t)(lane + k * 64) * 10;
            z2t += r[8]; zbt += r[9];
        }
        for (int i = lane; i < 1000; i += 64) {
            const double em = (double)counts[i] / (double)Nv;
            pl += em * log(em + 1e-10);
        }
#pragma unroll
        for (int m = 1; m < 64; m <<= 1) {
            csv += __shfl_xor(csv, m, 64);
            z2t += __shfl_xor(z2t, m, 64);
            zbt += __shfl_xor(zbt, m, 64);
            pl  += __shfl_xor(pl,  m, 64);
        }
        if (lane == 0) {
            out[out_size - 2] = (float)((z2t - 2.0 * zbt + csv) / (double)TOTv);
            out[out_size - 1] = (float)exp(-pl);
        }
    }
}

extern "C" void kernel_launch(void* const* d_in, const int* in_sizes, int n_in,
                              void* d_out, int out_size, void* d_ws, size_t ws_size,
                              hipStream_t stream) {
    const float* z     = (const float*)d_in[0];
    const float* W_in  = (const float*)d_in[1];
    const float* b_in  = (const float*)d_in[2];
    const float* gamma = (const float*)d_in[3];
    const float* beta  = (const float*)d_in[4];
    const float* W_out = (const float*)d_in[5];
    const float* b_out = (const float*)d_in[6];
    float* out = (float*)d_out;

    char* ws = (char*)d_ws;
    double*   bs     = (double*)(ws + OFF_BS);
    double*   gram   = (double*)(ws + OFF_GR);
    double*   cp     = (double*)(ws + OFF_CP);
    unsigned* counts = (unsigned*)(ws + OFF_CT);

    void* args[] = {(void*)&z, (void*)&W_in, (void*)&b_in, (void*)&gamma, (void*)&beta,
                    (void*)&W_out, (void*)&b_out, (void*)&out, (void*)&bs, (void*)&gram,
                    (void*)&cp, (void*)&counts, (void*)&out_size};
    hipLaunchCooperativeKernel((void*)fsq_main, dim3(NBLK), dim3(128), args, 0, stream);
}

// Round 4
// 193.394 us; speedup vs baseline: 1.5440x; 1.5440x over previous
//
#include <hip/hip_runtime.h>
#include <math.h>

// FSQuantizer v4: occupancy-first multi-kernel.
// z (32,512,4096) f32 -> zhat f32 + commit_loss + perplexity.
// kA: 2048 blocks (32b x 64tt), 256 thr = 64t x 4cs. Full h,g per row via LDS combine.
// kS: 1 block stats finalize (BN consts, Gram, zero counts).
// kC: 2048 blocks (32b x 16tt x 4ch), quantize + histogram + commit + zhat stores.
// kD: 1 block finalize scalars.

namespace {
constexpr int Cv = 512, Tv = 4096, Bv = 32;
constexpr int Nv = Bv * Tv;                       // 131072 rows
constexpr long long TOTv = (long long)Nv * Cv;    // 67108864
constexpr int NBA = 2048;                         // kA blocks
constexpr int NBC = 2048;                         // kC blocks
constexpr int NCP = 512;                          // commit partial slots (32b x 16tt)

// workspace layout (bytes)
constexpr size_t OFF_H  = 0;                                   // h_ws [Nv][4] f32 (2 MiB)
constexpr size_t OFF_G  = OFF_H  + (size_t)Nv * 16;            // g_ws [Nv][4] f32 (2 MiB)
constexpr size_t OFF_BS = OFF_G  + (size_t)Nv * 16;            // bs [NBA][10] f64 (160 KiB)
constexpr size_t OFF_CN = OFF_BS + (size_t)NBA * 10 * 8;       // consts [32] f64
constexpr size_t OFF_CP = OFF_CN + 32 * 8;                     // cp [NCP] f64
constexpr size_t OFF_CT = OFF_CP + (size_t)NCP * 8;            // counts [1024] u32
}

// ---- kA: stream z once, produce h,g per row + block stats ----
__global__ __launch_bounds__(256, 4) void fsq_kA(
    const float* __restrict__ z, const float* __restrict__ W_in,
    const float* __restrict__ b_in, const float* __restrict__ W_out,
    const float* __restrict__ b_out,
    float* __restrict__ h_ws, float* __restrict__ g_ws, double* __restrict__ bs)
{
    __shared__ float s_wi[512][4];
    __shared__ float s_wo[512][4];
    __shared__ float s_bo[512];
    __shared__ float red[4][8][64];   // [cs][k][tq], conflict-free
    __shared__ float redz[2][256];

    const int tid = threadIdx.x;
    const int bid = blockIdx.x;
    const int b = bid >> 6;            // 64 t-tiles per b
    const int t0 = (bid & 63) << 6;    // 64 t per block
    const int tq = tid & 63;
    const int cs = tid >> 6;
    const int cbase = cs << 7;         // 128 c per split

    for (int i = tid; i < 512; i += 256) {
        *(float4*)&s_wi[i][0] = *(const float4*)(W_in + i * 4);
        s_wo[i][0] = W_out[i];
        s_wo[i][1] = W_out[512 + i];
        s_wo[i][2] = W_out[1024 + i];
        s_wo[i][3] = W_out[1536 + i];
        s_bo[i] = b_out[i];
    }
    __syncthreads();

    float h0 = 0.f, h1 = 0.f, h2 = 0.f, h3 = 0.f;
    float g0 = 0.f, g1 = 0.f, g2 = 0.f, g3 = 0.f;
    float z2 = 0.f, zb = 0.f;
    const float* zp = z + ((size_t)b * Cv + cbase) * Tv + t0 + tq;
#pragma unroll 8
    for (int i = 0; i < 128; ++i) {
        const float zv = zp[(size_t)i * Tv];   // 256 B contiguous per wave-instr
        const float4 wi = *(const float4*)&s_wi[cbase + i][0];
        const float4 wo = *(const float4*)&s_wo[cbase + i][0];
        h0 = fmaf(zv, wi.x, h0); h1 = fmaf(zv, wi.y, h1);
        h2 = fmaf(zv, wi.z, h2); h3 = fmaf(zv, wi.w, h3);
        g0 = fmaf(zv, wo.x, g0); g1 = fmaf(zv, wo.y, g1);
        g2 = fmaf(zv, wo.z, g2); g3 = fmaf(zv, wo.w, g3);
        z2 = fmaf(zv, zv, z2);
        zb = fmaf(zv, s_bo[cbase + i], zb);
    }

    red[cs][0][tq] = h0; red[cs][1][tq] = h1; red[cs][2][tq] = h2; red[cs][3][tq] = h3;
    red[cs][4][tq] = g0; red[cs][5][tq] = g1; red[cs][6][tq] = g2; red[cs][7][tq] = g3;
    redz[0][tid] = z2; redz[1][tid] = zb;
    __syncthreads();
    for (int s = 128; s > 0; s >>= 1) {
        if (tid < s) { redz[0][tid] += redz[0][tid + s]; redz[1][tid] += redz[1][tid + s]; }
        __syncthreads();
    }

    if (tid < 64) {
        float hh[4], gg[4];
#pragma unroll
        for (int k = 0; k < 4; ++k)
            hh[k] = (red[0][k][tid] + red[1][k][tid]) + (red[2][k][tid] + red[3][k][tid]);
#pragma unroll
        for (int k = 0; k < 4; ++k)
            gg[k] = (red[0][4 + k][tid] + red[1][4 + k][tid]) + (red[2][4 + k][tid] + red[3][4 + k][tid]);
        hh[0] += b_in[0]; hh[1] += b_in[1]; hh[2] += b_in[2]; hh[3] += b_in[3];

        const int n = (b << 12) + t0 + tid;
        *(float4*)(h_ws + (size_t)n * 4) = make_float4(hh[0], hh[1], hh[2], hh[3]);
        *(float4*)(g_ws + (size_t)n * 4) = make_float4(gg[0], gg[1], gg[2], gg[3]);

        double st[8];
#pragma unroll
        for (int e = 0; e < 4; ++e) {
            st[e] = (double)hh[e];
            st[4 + e] = (double)hh[e] * (double)hh[e];
        }
#pragma unroll
        for (int k = 0; k < 8; ++k) {
#pragma unroll
            for (int m = 1; m < 64; m <<= 1) st[k] += __shfl_xor(st[k], m, 64);
        }
        if (tid == 0) {
            double* bp = bs + (size_t)bid * 10;
#pragma unroll
            for (int k = 0; k < 8; ++k) bp[k] = st[k];
            bp[8] = (double)redz[0][0];
            bp[9] = (double)redz[1][0];
        }
    }
}

// ---- kS: finalize BN consts + Gram + zero counts ----
__global__ __launch_bounds__(256) void fsq_kS(
    const float* __restrict__ gamma, const float* __restrict__ beta,
    const float* __restrict__ W_out, const float* __restrict__ b_out,
    const double* __restrict__ bs, double* __restrict__ consts,
    unsigned* __restrict__ counts)
{
    __shared__ double sbuf[15][256];
    const int tid = threadIdx.x;

    for (int i = tid; i < 1000; i += 256) counts[i] = 0;

    double a[10] = {};
    for (int r = tid; r < NBA; r += 256) {
        const double* p = bs + (size_t)r * 10;
#pragma unroll
        for (int k = 0; k < 10; ++k) a[k] += p[k];
    }
#pragma unroll
    for (int k = 0; k < 10; ++k) sbuf[k][tid] = a[k];
    __syncthreads();
    for (int s = 128; s > 0; s >>= 1) {
        if (tid < s) {
#pragma unroll
            for (int k = 0; k < 10; ++k) sbuf[k][tid] += sbuf[k][tid + s];
        }
        __syncthreads();
    }
    double tot[10];
    if (tid == 0) {
#pragma unroll
        for (int k = 0; k < 10; ++k) tot[k] = sbuf[k][0];
    }
    __syncthreads();

    // Gram of W_out rows + v + s0
    double gr[15] = {};
    for (int c = tid; c < 512; c += 256) {
        const double w0 = (double)W_out[c], w1 = (double)W_out[512 + c];
        const double w2 = (double)W_out[1024 + c], w3 = (double)W_out[1536 + c];
        const double bb = (double)b_out[c];
        gr[0] += w0 * w0; gr[1] += w0 * w1; gr[2] += w0 * w2; gr[3] += w0 * w3;
        gr[4] += w1 * w1; gr[5] += w1 * w2; gr[6] += w1 * w3;
        gr[7] += w2 * w2; gr[8] += w2 * w3; gr[9] += w3 * w3;
        gr[10] += w0 * bb; gr[11] += w1 * bb; gr[12] += w2 * bb; gr[13] += w3 * bb;
        gr[14] += bb * bb;
    }
#pragma unroll
    for (int k = 0; k < 15; ++k) sbuf[k][tid] = gr[k];
    __syncthreads();
    for (int s = 128; s > 0; s >>= 1) {
        if (tid < s) {
#pragma unroll
            for (int k = 0; k < 15; ++k) sbuf[k][tid] += sbuf[k][tid + s];
        }
        __syncthreads();
    }
    if (tid == 0) {
        const double Ninv = 1.0 / (double)Nv;
#pragma unroll
        for (int e = 0; e < 4; ++e) {
            const double mu = tot[e] * Ninv;
            const double var = tot[4 + e] * Ninv - mu * mu;   // biased, matches jnp.var
            const double sc = (double)gamma[e] / sqrt(var + 1e-5);
            consts[e] = sc;
            consts[4 + e] = (double)beta[e] - mu * sc;
        }
        consts[8] = tot[8];   // sum z^2
        consts[9] = tot[9];   // sum z.b_out
#pragma unroll
        for (int k = 0; k < 15; ++k) consts[16 + k] = sbuf[k][0];
        constexpr double hl0 = (8.0 - 1.0) * (1.0 - 1e-3) / 2.0;
        consts[31] = tan(0.5 / hl0);
    }
}

// ---- kC: quantize + histogram + commit partials + write zhat ----
__global__ __launch_bounds__(256, 4) void fsq_kC(
    const float* __restrict__ W_out, const float* __restrict__ b_out,
    const float* __restrict__ h_ws, const float* __restrict__ g_ws,
    const double* __restrict__ consts, unsigned* __restrict__ counts,
    double* __restrict__ cp, float* __restrict__ out)
{
    __shared__ float s_wo[128][4];
    __shared__ float s_bo[128];
    __shared__ double sred[256];

    const int tid = threadIdx.x;
    const int bid = blockIdx.x;
    const int b = bid >> 6;            // 64 blocks per b (16 tt x 4 ch)
    const int tt = (bid >> 2) & 15;
    const int ch = bid & 3;
    const int c0 = ch << 7;
    const int t0 = tt << 8;            // 256 t per block
    const int n = (b << 12) + t0 + tid;

    if (tid < 128) {
        const int c = c0 + tid;
        s_wo[tid][0] = W_out[c];
        s_wo[tid][1] = W_out[512 + c];
        s_wo[tid][2] = W_out[1024 + c];
        s_wo[tid][3] = W_out[1536 + c];
        s_bo[tid] = b_out[c];
    }
    __syncthreads();

    const double sc0 = consts[0], sc1 = consts[1], sc2 = consts[2], sc3 = consts[3];
    const double bi0 = consts[4], bi1 = consts[5], bi2 = consts[6], bi3 = consts[7];
    const double shift0 = consts[31];
    constexpr double hl0 = (8.0 - 1.0) * (1.0 - 1e-3) / 2.0;   // 3.4965
    constexpr double hl1 = (5.0 - 1.0) * (1.0 - 1e-3) / 2.0;   // 1.998

    const float4 hv = *(const float4*)(h_ws + (size_t)n * 4);
    const double hn0 = fma((double)hv.x, sc0, bi0);
    const double hn1 = fma((double)hv.y, sc1, bi1);
    const double hn2 = fma((double)hv.z, sc2, bi2);
    const double hn3 = fma((double)hv.w, sc3, bi3);
    const double r0 = rint(tanh(hn0 + shift0) * hl0 - 0.5);    // [-4,3]
    const double r1 = rint(tanh(hn1) * hl1);                   // [-2,2]
    const double r2 = rint(tanh(hn2) * hl1);
    const double r3 = rint(tanh(hn3) * hl1);
    const double zd0 = r0 * 0.25, zd1 = r1 * 0.5, zd2 = r2 * 0.5, zd3 = r3 * 0.5;
    const float zn0 = (float)zd0, zn1 = (float)zd1, zn2 = (float)zd2, zn3 = (float)zd3;

    if (ch == 0) {
        const int code = ((int)r0 + 4) + ((int)r1 + 2) * 8 + ((int)r2 + 2) * 40
                       + ((int)r3 + 2) * 200;
        atomicAdd(&counts[code], 1u);
        const float4 gv = *(const float4*)(g_ws + (size_t)n * 4);
        const double cg = zd0 * (double)gv.x + zd1 * (double)gv.y
                        + zd2 * (double)gv.z + zd3 * (double)gv.w;
        double q = consts[16 + 14]
                 + 2.0 * (zd0 * consts[16 + 10] + zd1 * consts[16 + 11]
                        + zd2 * consts[16 + 12] + zd3 * consts[16 + 13])
                 + zd0 * zd0 * consts[16 + 0] + zd1 * zd1 * consts[16 + 4]
                 + zd2 * zd2 * consts[16 + 7] + zd3 * zd3 * consts[16 + 9]
                 + 2.0 * (zd0 * zd1 * consts[16 + 1] + zd0 * zd2 * consts[16 + 2]
                        + zd0 * zd3 * consts[16 + 3] + zd1 * zd2 * consts[16 + 5]
                        + zd1 * zd3 * consts[16 + 6] + zd2 * zd3 * consts[16 + 8]);
        sred[tid] = q - 2.0 * cg;
        __syncthreads();
        for (int s = 128; s > 0; s >>= 1) {
            if (tid < s) sred[tid] += sred[tid + s];
            __syncthreads();
        }
        if (tid == 0) cp[(b << 4) + tt] = sred[0];
    }

    // write zhat slab: 4 B/lane, 256 B contiguous per wave-instr
    float* op = out + ((size_t)b * Cv + c0) * Tv + t0 + tid;
#pragma unroll 8
    for (int i = 0; i < 128; ++i) {
        const float4 wo = *(const float4*)&s_wo[i][0];
        float v = fmaf(zn0, wo.x, fmaf(zn1, wo.y, fmaf(zn2, wo.z, fmaf(zn3, wo.w, s_bo[i]))));
        op[(size_t)i * Tv] = v;
    }
}

// ---- kD: finalize scalars ----
__global__ __launch_bounds__(256) void fsq_kD(
    const double* __restrict__ cp, const double* __restrict__ consts,
    const unsigned* __restrict__ counts, float* __restrict__ out, int out_size)
{
    __shared__ double r1[256], r2[256];
    const int tid = threadIdx.x;
    double c_ = cp[tid] + cp[tid + 256];
    double pl = 0.0;
    for (int i = tid; i < 1000; i += 256) {
        const double em = (double)counts[i] / (double)Nv;
        pl += em * log(em + 1e-10);
    }
    r1[tid] = c_; r2[tid] = pl;
    __syncthreads();
    for (int s = 128; s > 0; s >>= 1) {
        if (tid < s) { r1[tid] += r1[tid + s]; r2[tid] += r2[tid + s]; }
        __syncthreads();
    }
    if (tid == 0) {
        const double commit = (consts[8] - 2.0 * consts[9] + r1[0]) / (double)TOTv;
        out[out_size - 2] = (float)commit;
        out[out_size - 1] = (float)exp(-r2[0]);
    }
}

extern "C" void kernel_launch(void* const* d_in, const int* in_sizes, int n_in,
                              void* d_out, int out_size, void* d_ws, size_t ws_size,
                              hipStream_t stream) {
    const float* z     = (const float*)d_in[0];
    const float* W_in  = (const float*)d_in[1];
    const float* b_in  = (const float*)d_in[2];
    const float* gamma = (const float*)d_in[3];
    const float* beta  = (const float*)d_in[4];
    const float* W_out = (const float*)d_in[5];
    const float* b_out = (const float*)d_in[6];
    float* out = (float*)d_out;

    char* ws = (char*)d_ws;
    float*    h_ws   = (float*)(ws + OFF_H);
    float*    g_ws   = (float*)(ws + OFF_G);
    double*   bs     = (double*)(ws + OFF_BS);
    double*   consts = (double*)(ws + OFF_CN);
    double*   cp     = (double*)(ws + OFF_CP);
    unsigned* counts = (unsigned*)(ws + OFF_CT);

    fsq_kA<<<NBA, 256, 0, stream>>>(z, W_in, b_in, W_out, b_out, h_ws, g_ws, bs);
    fsq_kS<<<1, 256, 0, stream>>>(gamma, beta, W_out, b_out, bs, consts, counts);
    fsq_kC<<<NBC, 256, 0, stream>>>(W_out, b_out, h_ws, g_ws, consts, counts, cp, out);
    fsq_kD<<<1, 256, 0, stream>>>(cp, consts, counts, out, out_size);
}